// Round 5
// baseline (1511.931 us; speedup 1.0000x reference)
//
#include <hip/hip_runtime.h>
#include <math.h>

#define KNNK 20
#define BEFORE(v1, g1, v2, g2) (((v1) > (v2)) || ((v1) == (v2) && (g1) < (g2)))

__device__ __forceinline__ float lrelu(float v) { return v >= 0.f ? v : 0.2f * v; }

// ---------------- xx[b][n] = sum_c f[b][c][n]^2 ----------------
__global__ __launch_bounds__(256) void xx_kernel(const float* __restrict__ f, long bstride, int C,
                                                 float* __restrict__ xx) {
    int i = blockIdx.x * 256 + threadIdx.x;   // over B*N
    int b = i >> 11, n = i & 2047;
    const float* fb = f + (long)b * bstride;
    float s = 0.f;
    for (int c = 0; c < C; ++c) { float v = fb[c * 2048 + n]; s = fmaf(v, v, s); }
    xx[i] = s;
}

// ---------------- KNN: 8-row strip, 1024 threads, 2 waves per row ----------------
// Gram: thread owns 4 rows x 4 cols (bit-identical fmaf order to prior rounds).
// Selection: wave (row,half) sorts its 1024-col half exactly (top-3 build + 128-cand
// bitonic + repair), halves merged by a 64-lane bitonic in (value desc, index asc)
// = exact JAX top_k order. LDS stays 64 KB -> 2 blocks/CU = 32 waves/CU.
__global__ __launch_bounds__(1024, 8) void knn_kernel(const float* __restrict__ f, long bstride, int C,
                                                      const float* __restrict__ xx, int* __restrict__ idx_out) {
    __shared__ __align__(16) float lds[8 * 2048];
    int b = blockIdx.y;
    int n0 = blockIdx.x * 8;
    int t = threadIdx.x;
    const float* fb = f + (long)b * bstride;

    // stage center block A[c][j] = f[c][n0+j]
    for (int e = t; e < C * 8; e += 1024) {
        int c = e >> 3, j = e & 7;
        lds[e] = fb[c * 2048 + n0 + j];
    }
    __syncthreads();

    // Gram: rows r0..r0+3, cols m0..m0+3
    int rhalf = t >> 9;          // 0/1
    int r0 = rhalf * 4;
    int m0 = (t & 511) * 4;
    float acc[4][4];
#pragma unroll
    for (int i = 0; i < 4; ++i)
#pragma unroll
        for (int j = 0; j < 4; ++j) acc[i][j] = 0.f;
    for (int c = 0; c < C; ++c) {
        float4 b4 = *(const float4*)(fb + c * 2048 + m0);
        float bv4[4] = {b4.x, b4.y, b4.z, b4.w};
        float4 a4 = *(const float4*)(lds + c * 8 + r0);
        float av4[4] = {a4.x, a4.y, a4.z, a4.w};
#pragma unroll
        for (int i = 0; i < 4; ++i)
#pragma unroll
            for (int j = 0; j < 4; ++j) acc[i][j] = fmaf(av4[i], bv4[j], acc[i][j]);
    }
    float xn[4];
#pragma unroll
    for (int i = 0; i < 4; ++i) xn[i] = xx[b * 2048 + n0 + r0 + i];
    float4 xm4 = *(const float4*)(xx + b * 2048 + m0);
    float xm[4] = {xm4.x, xm4.y, xm4.z, xm4.w};

    __syncthreads();   // A region fully consumed
#pragma unroll
    for (int i = 0; i < 4; ++i) {
        float4 o;
        o.x = (2.f * acc[i][0] - xn[i]) - xm[0];
        o.y = (2.f * acc[i][1] - xn[i]) - xm[1];
        o.z = (2.f * acc[i][2] - xn[i]) - xm[2];
        o.w = (2.f * acc[i][3] - xn[i]) - xm[3];
        *(float4*)(lds + (r0 + i) * 2048 + m0) = o;
    }
    __syncthreads();

    // ---- selection: wave = (row, half) over 1024 cols ----
    int wave = t >> 6, lane = t & 63;
    int row = wave >> 1, h = wave & 1;
    const float* srow = lds + row * 2048 + h * 1024;
    int gbase = (h << 10) + lane;   // global col = gbase + (j<<6)
    float v[16];
#pragma unroll
    for (int j = 0; j < 16; ++j) v[j] = srow[lane + 64 * j];

    // per-lane top-3 (strict '>' keeps earliest index among equals)
    float b1 = -INFINITY, b2 = -INFINITY, b3 = -INFINITY;
    int j1 = 0, j2 = 0, j3 = 0;
#pragma unroll
    for (int j = 0; j < 16; ++j) {
        float vv = v[j];
        bool c1 = vv > b1;
        bool c2 = vv > b2;
        bool c3 = vv > b3;
        b3 = c2 ? b2 : (c3 ? vv : b3);
        j3 = c2 ? j2 : (c3 ? j : j3);
        b2 = c1 ? b1 : (c2 ? vv : b2);
        j2 = c1 ? j1 : (c2 ? j : j2);
        b1 = c1 ? vv : b1;
        j1 = c1 ? j : j1;
    }

    // bitonic sort of 128 candidates (2 per lane)
    float av = b1, bv = b2;
    int ag = gbase + (j1 << 6), bg = gbase + (j2 << 6);
#pragma unroll
    for (int size = 2; size <= 128; size <<= 1) {
#pragma unroll
        for (int stride = size >> 1; stride >= 1; stride >>= 1) {
            if (stride == 64) {
                bool keep = BEFORE(av, ag, bv, bg);
                float tv = keep ? av : bv;
                int tg = keep ? ag : bg;
                bv = keep ? bv : av; bg = keep ? bg : ag;
                av = tv; ag = tg;
            } else {
                float oav = __shfl_xor(av, stride), obv = __shfl_xor(bv, stride);
                int oag = __shfl_xor(ag, stride), obg = __shfl_xor(bg, stride);
                bool low = (lane & stride) == 0;
                bool ascA = (lane & size) == 0;
                bool ascB = (((64 + lane) & size) == 0);
                bool fA = BEFORE(av, ag, oav, oag);
                bool fB = BEFORE(bv, bg, obv, obg);
                bool tA = (low == ascA) ? fA : !fA;
                bool tB = (low == ascB) ? fB : !fB;
                av = tA ? av : oav; ag = tA ? ag : oag;
                bv = tB ? bv : obv; bg = tB ? bg : obg;
            }
        }
    }
    // lanes 0..19 hold the half's ranks 0..19

    // repair: lane whose top-2 both placed may owe its 3rd(+)
    float wv19 = __shfl(av, 19);
    int wg19 = __shfl(ag, 19);
    unsigned used = (1u << j1) | (1u << j2) | (1u << j3);
    float pv = b3;
    int pg = gbase + (j3 << 6);
    while (__any(BEFORE(pv, pg, wv19, wg19))) {
        unsigned long long act = __ballot(BEFORE(pv, pg, wv19, wg19));
        int L = __ffsll(act) - 1;
        float cv = __shfl(pv, L);
        int cg2 = __shfl(pg, L);
        unsigned long long cfb = __ballot(lane < 20 && BEFORE(cv, cg2, av, ag));
        int p = 20 - __popcll(cfb);
        float upv = __shfl_up(av, 1);
        int upg = __shfl_up(ag, 1);
        if (lane < 20) {
            if (lane > p) { av = upv; ag = upg; }
            else if (lane == p) { av = cv; ag = cg2; }
        }
        if (lane == L) {
            float nb = -INFINITY;
            int nj = 0;
#pragma unroll
            for (int j = 0; j < 16; ++j) {
                float vvv = ((used >> j) & 1u) ? -INFINITY : v[j];
                if (vvv > nb) { nb = vvv; nj = j; }
            }
            used |= 1u << nj;
            pv = nb;
            pg = gbase + (nj << 6);
        }
        wv19 = __shfl(av, 19);
        wg19 = __shfl(ag, 19);
    }

    // ---- merge the two half-top-20s (distances dead; reuse LDS start) ----
    // layout: values at [row*80 + h*20 + lane], indices (ints) at 640 + same
    __syncthreads();
    if (lane < KNNK) {
        lds[row * 80 + h * 20 + lane] = av;
        ((int*)lds)[640 + row * 80 + h * 20 + lane] = ag;
    }
    __syncthreads();
    if (wave < 8) {
        int r = wave;
        float mv = (lane < 40) ? lds[r * 80 + lane] : -INFINITY;
        int mg = (lane < 40) ? ((int*)lds)[640 + r * 80 + lane] : 0x7fffffff;
#pragma unroll
        for (int size = 2; size <= 64; size <<= 1) {
#pragma unroll
            for (int stride = size >> 1; stride >= 1; stride >>= 1) {
                float ov = __shfl_xor(mv, stride);
                int og = __shfl_xor(mg, stride);
                bool low = (lane & stride) == 0;
                bool asc = (lane & size) == 0;
                bool fwd = BEFORE(mv, mg, ov, og);
                bool take = (low == asc) ? fwd : !fwd;
                mv = take ? mv : ov;
                mg = take ? mg : og;
            }
        }
        if (lane < KNNK) idx_out[((long)b * 2048 + n0 + r) * KNNK + lane] = mg;
    }
}

// ---------------- P = Wa @ f, Q = (Wb - Wa) @ f, stored (B, N, 64) n-major ----------------
__global__ __launch_bounds__(256) void pq_kernel(const float* __restrict__ f, long bstride, int C,
                                                 const float* __restrict__ W, float* __restrict__ P,
                                                 float* __restrict__ Q) {
    __shared__ __align__(16) float wa[64 * 64];
    __shared__ __align__(16) float wq[64 * 64];
    __shared__ __align__(16) float X[64 * 64];
    int b = blockIdx.y, n0 = blockIdx.x * 64, t = threadIdx.x;
    const float* fb = f + (long)b * bstride;
    for (int e = t; e < C * 64; e += 256) {
        int k = e >> 6, c = e & 63;
        float a = W[c * 2 * C + k];
        float bv = W[c * 2 * C + C + k];
        wa[k * 64 + c] = a;
        wq[k * 64 + c] = bv - a;
    }
    for (int e = t; e < C * 64; e += 256) {
        int k = e >> 6, j = e & 63;
        X[e] = fb[k * 2048 + n0 + j];
    }
    __syncthreads();
    int cg = t >> 4, ng = t & 15;
    float accP[4][4] = {}, accQ[4][4] = {};
    for (int k = 0; k < C; ++k) {
        float4 a4 = *(const float4*)(wa + k * 64 + cg * 4);
        float4 q4 = *(const float4*)(wq + k * 64 + cg * 4);
        float4 x4 = *(const float4*)(X + k * 64 + ng * 4);
        float av[4] = {a4.x, a4.y, a4.z, a4.w};
        float qv[4] = {q4.x, q4.y, q4.z, q4.w};
        float xv[4] = {x4.x, x4.y, x4.z, x4.w};
#pragma unroll
        for (int i = 0; i < 4; ++i)
#pragma unroll
            for (int j = 0; j < 4; ++j) {
                accP[i][j] = fmaf(av[i], xv[j], accP[i][j]);
                accQ[i][j] = fmaf(qv[i], xv[j], accQ[i][j]);
            }
    }
#pragma unroll
    for (int j = 0; j < 4; ++j) {
        long n = n0 + ng * 4 + j;
        float4 pv = {accP[0][j], accP[1][j], accP[2][j], accP[3][j]};
        float4 qv = {accQ[0][j], accQ[1][j], accQ[2][j], accQ[3][j]};
        *(float4*)(P + ((long)b * 2048 + n) * 64 + cg * 4) = pv;
        *(float4*)(Q + ((long)b * 2048 + n) * 64 + cg * 4) = qv;
    }
}

// ---------------- EdgeConv layer-2 + max over k, fused (stages 1 & 2) ----------------
__global__ __launch_bounds__(256) void edge2_kernel(
    const float* __restrict__ P, const float* __restrict__ Q, const int* __restrict__ idx,
    const float* __restrict__ W2, const float* __restrict__ sa, const float* __restrict__ ta,
    const float* __restrict__ sb, const float* __restrict__ tb, float* __restrict__ out, int cofs) {
    __shared__ __align__(16) float h1[64 * 164];   // [cin][col], padded
    __shared__ __align__(16) float w2l[64 * 64];   // [cin][cout]
    __shared__ int idxl[160];
    int b = blockIdx.y, n0 = blockIdx.x * 8, t = threadIdx.x;
    if (t < 160) idxl[t] = idx[((long)b * 2048 + n0) * KNNK + t];
    for (int e = t; e < 4096; e += 256) { int co = e >> 6, ci = e & 63; w2l[ci * 64 + co] = W2[e]; }
    __syncthreads();
    for (int it = t; it < 2560; it += 256) {   // 160 cols x 16 channel-quads
        int col = it % 160, cg = it / 160;
        int p = col / 20;
        int j = idxl[col];
        int n = n0 + p;
        float4 pv = *(const float4*)(P + ((long)b * 2048 + j) * 64 + cg * 4);
        float4 qv = *(const float4*)(Q + ((long)b * 2048 + n) * 64 + cg * 4);
        float4 sv = *(const float4*)(sa + cg * 4);
        float4 tv = *(const float4*)(ta + cg * 4);
        h1[(cg * 4 + 0) * 164 + col] = lrelu(fmaf(sv.x, pv.x + qv.x, tv.x));
        h1[(cg * 4 + 1) * 164 + col] = lrelu(fmaf(sv.y, pv.y + qv.y, tv.y));
        h1[(cg * 4 + 2) * 164 + col] = lrelu(fmaf(sv.z, pv.z + qv.z, tv.z));
        h1[(cg * 4 + 3) * 164 + col] = lrelu(fmaf(sv.w, pv.w + qv.w, tv.w));
    }
    __syncthreads();
    int p = t & 7, co2 = t >> 3, c0 = co2 * 2;
    float acc0[20], acc1[20];
#pragma unroll
    for (int q = 0; q < 20; ++q) { acc0[q] = 0.f; acc1[q] = 0.f; }
#pragma unroll 4
    for (int k = 0; k < 64; ++k) {
        float2 w = *(const float2*)(w2l + k * 64 + c0);
        const float* hr = h1 + k * 164 + p * 20;
#pragma unroll
        for (int q = 0; q < 5; ++q) {
            float4 h4 = *(const float4*)(hr + q * 4);
            acc0[q * 4 + 0] = fmaf(w.x, h4.x, acc0[q * 4 + 0]);
            acc0[q * 4 + 1] = fmaf(w.x, h4.y, acc0[q * 4 + 1]);
            acc0[q * 4 + 2] = fmaf(w.x, h4.z, acc0[q * 4 + 2]);
            acc0[q * 4 + 3] = fmaf(w.x, h4.w, acc0[q * 4 + 3]);
            acc1[q * 4 + 0] = fmaf(w.y, h4.x, acc1[q * 4 + 0]);
            acc1[q * 4 + 1] = fmaf(w.y, h4.y, acc1[q * 4 + 1]);
            acc1[q * 4 + 2] = fmaf(w.y, h4.z, acc1[q * 4 + 2]);
            acc1[q * 4 + 3] = fmaf(w.y, h4.w, acc1[q * 4 + 3]);
        }
    }
    float s0 = sb[c0], t0v = tb[c0], s1 = sb[c0 + 1], t1v = tb[c0 + 1];
    float m0 = -INFINITY, m1 = -INFINITY;
#pragma unroll
    for (int q = 0; q < 20; ++q) {
        m0 = fmaxf(m0, lrelu(fmaf(s0, acc0[q], t0v)));
        m1 = fmaxf(m1, lrelu(fmaf(s1, acc1[q], t1v)));
    }
    out[(long)b * (192 * 2048) + (long)(cofs + c0) * 2048 + n0 + p] = m0;
    out[(long)b * (192 * 2048) + (long)(cofs + c0 + 1) * 2048 + n0 + p] = m1;
}

// ---------------- Stage 3: gather + affine + lrelu + max over k ----------------
__global__ __launch_bounds__(256) void edge1_kernel(const float* __restrict__ P, const float* __restrict__ Q,
                                                    const int* __restrict__ idx, const float* __restrict__ s,
                                                    const float* __restrict__ tt, float* __restrict__ out,
                                                    int cofs) {
    __shared__ int idxl[80];
    int b = blockIdx.y, n0 = blockIdx.x * 4, t = threadIdx.x;
    int c = t & 63, p = t >> 6;
    if (t < 80) idxl[t] = idx[((long)b * 2048 + n0) * KNNK + t];
    __syncthreads();
    float qv = Q[((long)b * 2048 + n0 + p) * 64 + c];
    float sc = s[c], tc = tt[c];
    float m = -INFINITY;
    for (int kk = 0; kk < KNNK; ++kk) {
        int j = idxl[p * KNNK + kk];
        float v = P[((long)b * 2048 + j) * 64 + c];
        m = fmaxf(m, lrelu(fmaf(sc, v + qv, tc)));
    }
    out[(long)b * (192 * 2048) + (long)(cofs + c) * 2048 + n0 + p] = m;
}

// ---------------- Generic head GEMM: 128x128 tile, 8x8 per thread ----------------
// cg = t>>4 owns rows ct+cg*8..+7; ng = t&15 owns cols nt+ng*4..+3 and nt+64+ng*4..+3.
__global__ __launch_bounds__(256, 4) void gemm_kernel(
    const float* __restrict__ W, int ldw, int Kdim, const float* __restrict__ X, long xbstride,
    const float* __restrict__ s, const float* __restrict__ tvec, const float* __restrict__ bias, int M,
    float* __restrict__ out, long obstride, float* __restrict__ maxout) {
    __shared__ __align__(16) float wl[32 * 132];
    __shared__ __align__(16) float xl[32 * 132];
    int b = blockIdx.z, ct = blockIdx.x * 128, nt = blockIdx.y * 128, t = threadIdx.x;
    const float* Xb = X + (long)b * xbstride;
    int cg = t >> 4, ng = t & 15;
    float acc[8][8];
#pragma unroll
    for (int i = 0; i < 8; ++i)
#pragma unroll
        for (int j = 0; j < 8; ++j) acc[i][j] = 0.f;
    for (int k0 = 0; k0 < Kdim; k0 += 32) {
        __syncthreads();
        for (int e = t; e < 4096; e += 256) {
            int k = e & 31, c = e >> 5;
            wl[k * 132 + c] = W[(long)(ct + c) * ldw + k0 + k];
        }
        for (int e = t; e < 4096; e += 256) {
            int k = e >> 7, j = e & 127;
            xl[k * 132 + j] = Xb[(long)(k0 + k) * 2048 + nt + j];
        }
        __syncthreads();
#pragma unroll 4
        for (int k = 0; k < 32; ++k) {
            float4 wa4 = *(const float4*)(wl + k * 132 + cg * 8);
            float4 wb4 = *(const float4*)(wl + k * 132 + cg * 8 + 4);
            float4 xa4 = *(const float4*)(xl + k * 132 + ng * 4);
            float4 xb4 = *(const float4*)(xl + k * 132 + 64 + ng * 4);
            float wv[8] = {wa4.x, wa4.y, wa4.z, wa4.w, wb4.x, wb4.y, wb4.z, wb4.w};
            float xv[8] = {xa4.x, xa4.y, xa4.z, xa4.w, xb4.x, xb4.y, xb4.z, xb4.w};
#pragma unroll
            for (int i = 0; i < 8; ++i)
#pragma unroll
                for (int j = 0; j < 8; ++j) acc[i][j] = fmaf(wv[i], xv[j], acc[i][j]);
        }
    }
    if (maxout) {
        __syncthreads();
        float* scr = xl;   // 128 x 16 reuse
#pragma unroll
        for (int i = 0; i < 8; ++i) {
            int c = ct + cg * 8 + i;
            float sv = s[c], tv = tvec[c];
            float m = -INFINITY;
#pragma unroll
            for (int j = 0; j < 8; ++j) m = fmaxf(m, lrelu(fmaf(sv, acc[i][j], tv)));
            scr[(cg * 8 + i) * 16 + ng] = m;
        }
        __syncthreads();
        if (t < 128) {
            float m = scr[t * 16];
            for (int j = 1; j < 16; ++j) m = fmaxf(m, scr[t * 16 + j]);
            maxout[((long)b * M + ct + t) * 16 + blockIdx.y] = m;
        }
    } else {
#pragma unroll
        for (int i = 0; i < 8; ++i) {
            int c = ct + cg * 8 + i;
            float bv = bias ? bias[b * M + c] : 0.f;
            float sv = s[c], tv = tvec[c];
            float4 o0, o1;
            o0.x = lrelu(fmaf(sv, acc[i][0] + bv, tv));
            o0.y = lrelu(fmaf(sv, acc[i][1] + bv, tv));
            o0.z = lrelu(fmaf(sv, acc[i][2] + bv, tv));
            o0.w = lrelu(fmaf(sv, acc[i][3] + bv, tv));
            o1.x = lrelu(fmaf(sv, acc[i][4] + bv, tv));
            o1.y = lrelu(fmaf(sv, acc[i][5] + bv, tv));
            o1.z = lrelu(fmaf(sv, acc[i][6] + bv, tv));
            o1.w = lrelu(fmaf(sv, acc[i][7] + bv, tv));
            float* op = out + (long)b * obstride + (long)c * 2048 + nt + ng * 4;
            *(float4*)op = o0;
            *(float4*)(op + 64) = o1;
        }
    }
}

// ---------------- finalize g = max over the 16 n-tile partials ----------------
__global__ __launch_bounds__(256) void gmax_final(const float* __restrict__ ep, float* __restrict__ g) {
    int i = blockIdx.x * 256 + threadIdx.x;   // < 16*1024
    float m = ep[i * 16];
    for (int j = 1; j < 16; ++j) m = fmaxf(m, ep[i * 16 + j]);
    g[i] = m;
}

// ---------------- bias7[b][co] = w7[co, :1024] @ g[b] ----------------
__global__ __launch_bounds__(64) void bias7_kernel(const float* __restrict__ w7, const float* __restrict__ g,
                                                   float* __restrict__ bias7) {
    int o = blockIdx.x;            // b*512 + co
    int b = o >> 9, co = o & 511;
    int lane = threadIdx.x;
    float acc = 0.f;
    for (int j = lane; j < 1024; j += 64) acc = fmaf(w7[(long)co * 1216 + j], g[b * 1024 + j], acc);
#pragma unroll
    for (int off = 32; off >= 1; off >>= 1) acc += __shfl_xor(acc, off);
    if (lane == 0) bias7[o] = acc;
}

// ---------------- y[b][n] = sigmoid(w9 @ h8[:, n]) ----------------
__global__ __launch_bounds__(256) void w9_kernel(const float* __restrict__ w9, const float* __restrict__ h8,
                                                 float* __restrict__ out) {
    int i = blockIdx.x * 256 + threadIdx.x;   // over B*N
    int b = i >> 11, n = i & 2047;
    const float* hb = h8 + (long)b * 256 * 2048 + n;
    float acc = 0.f;
    for (int c = 0; c < 256; ++c) acc = fmaf(w9[c], hb[c * 2048], acc);
    out[i] = 1.f / (1.f + expf(-acc));
}

extern "C" void kernel_launch(void* const* d_in, const int* in_sizes, int n_in,
                              void* d_out, int out_size, void* d_ws, size_t ws_size,
                              hipStream_t stream) {
    (void)in_sizes; (void)n_in; (void)out_size; (void)ws_size;
    const float* x  = (const float*)d_in[0];
    const float* w1 = (const float*)d_in[1];
    const float* w2 = (const float*)d_in[2];
    const float* w3 = (const float*)d_in[3];
    const float* w4 = (const float*)d_in[4];
    const float* w5 = (const float*)d_in[5];
    const float* w6 = (const float*)d_in[6];
    const float* w7 = (const float*)d_in[7];
    const float* w8 = (const float*)d_in[8];
    const float* w9 = (const float*)d_in[9];
    const float* s1 = (const float*)d_in[10]; const float* t1 = (const float*)d_in[11];
    const float* s2 = (const float*)d_in[12]; const float* t2 = (const float*)d_in[13];
    const float* s3 = (const float*)d_in[14]; const float* t3 = (const float*)d_in[15];
    const float* s4 = (const float*)d_in[16]; const float* t4 = (const float*)d_in[17];
    const float* s5 = (const float*)d_in[18]; const float* t5 = (const float*)d_in[19];
    const float* s6 = (const float*)d_in[20]; const float* t6 = (const float*)d_in[21];
    const float* s7 = (const float*)d_in[22]; const float* t7 = (const float*)d_in[23];
    const float* s8 = (const float*)d_in[24]; const float* t8 = (const float*)d_in[25];

    // workspace partition (floats)
    float* cat = (float*)d_ws;                          // 16*192*2048
    float* xxb = cat + (long)16 * 192 * 2048;           // 16*2048
    int*   idxb = (int*)(xxb + 16 * 2048);              // 16*2048*20 ints
    float* P  = (float*)(idxb + (long)16 * 2048 * 20);  // 16*2048*64
    float* Q  = P + (long)16 * 2048 * 64;               // 16*2048*64
    float* ep = Q + (long)16 * 2048 * 64;               // 16*1024*16
    float* g  = ep + 16 * 1024 * 16;                    // 16*1024
    float* b7 = g + 16 * 1024;                          // 16*512
    float* h7 = b7 + 16 * 512;                          // 16*512*2048
    float* h8 = h7 + (long)16 * 512 * 2048;             // 16*256*2048

    dim3 blk(256);
    dim3 blk1024(1024);
    long catstride = 192 * 2048;

    // ---- stage 1 (C=2) ----
    xx_kernel<<<128, blk, 0, stream>>>(x, 2 * 2048, 2, xxb);
    knn_kernel<<<dim3(256, 16), blk1024, 0, stream>>>(x, 2 * 2048, 2, xxb, idxb);
    pq_kernel<<<dim3(32, 16), blk, 0, stream>>>(x, 2 * 2048, 2, w1, P, Q);
    edge2_kernel<<<dim3(256, 16), blk, 0, stream>>>(P, Q, idxb, w2, s1, t1, s2, t2, cat, 0);
    // ---- stage 2 (C=64 on x1) ----
    xx_kernel<<<128, blk, 0, stream>>>(cat, catstride, 64, xxb);
    knn_kernel<<<dim3(256, 16), blk1024, 0, stream>>>(cat, catstride, 64, xxb, idxb);
    pq_kernel<<<dim3(32, 16), blk, 0, stream>>>(cat, catstride, 64, w3, P, Q);
    edge2_kernel<<<dim3(256, 16), blk, 0, stream>>>(P, Q, idxb, w4, s3, t3, s4, t4, cat, 64);
    // ---- stage 3 (C=64 on x2) ----
    xx_kernel<<<128, blk, 0, stream>>>(cat + 64 * 2048, catstride, 64, xxb);
    knn_kernel<<<dim3(256, 16), blk1024, 0, stream>>>(cat + 64 * 2048, catstride, 64, xxb, idxb);
    pq_kernel<<<dim3(32, 16), blk, 0, stream>>>(cat + 64 * 2048, catstride, 64, w5, P, Q);
    edge1_kernel<<<dim3(512, 16), blk, 0, stream>>>(P, Q, idxb, s5, t5, cat, 128);
    // ---- head ----
    gemm_kernel<<<dim3(8, 16, 16), blk, 0, stream>>>(w6, 192, 192, cat, catstride, s6, t6, nullptr, 1024,
                                                     nullptr, 0, ep);
    gmax_final<<<64, blk, 0, stream>>>(ep, g);
    bias7_kernel<<<dim3(16 * 512), dim3(64), 0, stream>>>(w7, g, b7);
    gemm_kernel<<<dim3(4, 16, 16), blk, 0, stream>>>(w7 + 1024, 1216, 192, cat, catstride, s7, t7, b7, 512,
                                                     h7, (long)512 * 2048, nullptr);
    gemm_kernel<<<dim3(2, 16, 16), blk, 0, stream>>>(w8, 512, 512, h7, (long)512 * 2048, s8, t8, nullptr, 256,
                                                     h8, (long)256 * 2048, nullptr);
    w9_kernel<<<128, blk, 0, stream>>>(w9, h8, (float*)d_out);
}

// Round 6
// 1449.488 us; speedup vs baseline: 1.0431x; 1.0431x over previous
//
#include <hip/hip_runtime.h>
#include <math.h>

#define KNNK 20
#define BEFORE(v1, g1, v2, g2) (((v1) > (v2)) || ((v1) == (v2) && (g1) < (g2)))

__device__ __forceinline__ float lrelu(float v) { return v >= 0.f ? v : 0.2f * v; }

// ---------------- xx[b][n] = sum_c f[b][c][n]^2 ----------------
__global__ __launch_bounds__(256) void xx_kernel(const float* __restrict__ f, long bstride, int C,
                                                 float* __restrict__ xx) {
    int i = blockIdx.x * 256 + threadIdx.x;   // over B*N
    int b = i >> 11, n = i & 2047;
    const float* fb = f + (long)b * bstride;
    float s = 0.f;
    for (int c = 0; c < C; ++c) { float v = fb[c * 2048 + n]; s = fmaf(v, v, s); }
    xx[i] = s;
}

// ---------------- KNN: 4-row strip, 512 threads, 2 waves per row ----------------
// LDS 32 KB -> 4 blocks/CU = 32 waves/CU. launch_bounds(512,4) = VGPR cap 128 (no forced spill).
// Gram: thread owns 4 rows x 4 cols (bit-identical fmaf order to prior rounds).
// Selection: wave (row,half) sorts its 1024-col half exactly (top-3 build + 128-cand
// bitonic + repair), halves merged by a 64-lane bitonic in (value desc, index asc).
__global__ __launch_bounds__(512, 4) void knn_kernel(const float* __restrict__ f, long bstride, int C,
                                                     const float* __restrict__ xx, int* __restrict__ idx_out) {
    __shared__ __align__(16) float lds[4 * 2048];
    int b = blockIdx.y;
    int n0 = blockIdx.x * 4;
    int t = threadIdx.x;
    const float* fb = f + (long)b * bstride;

    // stage center block A[c][j] = f[c][n0+j]
    for (int e = t; e < C * 4; e += 512) {
        int c = e >> 2, j = e & 3;
        lds[e] = fb[c * 2048 + n0 + j];
    }
    __syncthreads();

    // Gram: all 4 rows, cols m0..m0+3
    int m0 = t * 4;
    float acc[4][4];
#pragma unroll
    for (int i = 0; i < 4; ++i)
#pragma unroll
        for (int j = 0; j < 4; ++j) acc[i][j] = 0.f;
    for (int c = 0; c < C; ++c) {
        float4 b4 = *(const float4*)(fb + c * 2048 + m0);
        float bv4[4] = {b4.x, b4.y, b4.z, b4.w};
        float4 a4 = *(const float4*)(lds + c * 4);
        float av4[4] = {a4.x, a4.y, a4.z, a4.w};
#pragma unroll
        for (int i = 0; i < 4; ++i)
#pragma unroll
            for (int j = 0; j < 4; ++j) acc[i][j] = fmaf(av4[i], bv4[j], acc[i][j]);
    }
    float xn[4];
#pragma unroll
    for (int i = 0; i < 4; ++i) xn[i] = xx[b * 2048 + n0 + i];
    float4 xm4 = *(const float4*)(xx + b * 2048 + m0);
    float xm[4] = {xm4.x, xm4.y, xm4.z, xm4.w};

    __syncthreads();   // A region fully consumed
#pragma unroll
    for (int i = 0; i < 4; ++i) {
        float4 o;
        o.x = (2.f * acc[i][0] - xn[i]) - xm[0];
        o.y = (2.f * acc[i][1] - xn[i]) - xm[1];
        o.z = (2.f * acc[i][2] - xn[i]) - xm[2];
        o.w = (2.f * acc[i][3] - xn[i]) - xm[3];
        *(float4*)(lds + i * 2048 + m0) = o;
    }
    __syncthreads();

    // ---- selection: wave = (row, half) over 1024 cols ----
    int wave = t >> 6, lane = t & 63;
    int row = wave >> 1, h = wave & 1;
    const float* srow = lds + row * 2048 + h * 1024;
    int gbase = (h << 10) + lane;   // global col = gbase + (j<<6)
    float v[16];
#pragma unroll
    for (int j = 0; j < 16; ++j) v[j] = srow[lane + 64 * j];

    // per-lane top-3 (strict '>' keeps earliest index among equals)
    float b1 = -INFINITY, b2 = -INFINITY, b3 = -INFINITY;
    int j1 = 0, j2 = 0, j3 = 0;
#pragma unroll
    for (int j = 0; j < 16; ++j) {
        float vv = v[j];
        bool c1 = vv > b1;
        bool c2 = vv > b2;
        bool c3 = vv > b3;
        b3 = c2 ? b2 : (c3 ? vv : b3);
        j3 = c2 ? j2 : (c3 ? j : j3);
        b2 = c1 ? b1 : (c2 ? vv : b2);
        j2 = c1 ? j1 : (c2 ? j : j2);
        b1 = c1 ? vv : b1;
        j1 = c1 ? j : j1;
    }

    // bitonic sort of 128 candidates (2 per lane)
    float av = b1, bv = b2;
    int ag = gbase + (j1 << 6), bg = gbase + (j2 << 6);
#pragma unroll
    for (int size = 2; size <= 128; size <<= 1) {
#pragma unroll
        for (int stride = size >> 1; stride >= 1; stride >>= 1) {
            if (stride == 64) {
                bool keep = BEFORE(av, ag, bv, bg);
                float tv = keep ? av : bv;
                int tg = keep ? ag : bg;
                bv = keep ? bv : av; bg = keep ? bg : ag;
                av = tv; ag = tg;
            } else {
                float oav = __shfl_xor(av, stride), obv = __shfl_xor(bv, stride);
                int oag = __shfl_xor(ag, stride), obg = __shfl_xor(bg, stride);
                bool low = (lane & stride) == 0;
                bool ascA = (lane & size) == 0;
                bool ascB = (((64 + lane) & size) == 0);
                bool fA = BEFORE(av, ag, oav, oag);
                bool fB = BEFORE(bv, bg, obv, obg);
                bool tA = (low == ascA) ? fA : !fA;
                bool tB = (low == ascB) ? fB : !fB;
                av = tA ? av : oav; ag = tA ? ag : oag;
                bv = tB ? bv : obv; bg = tB ? bg : obg;
            }
        }
    }
    // lanes 0..19 hold the half's ranks 0..19

    // repair: lane whose top-2 both placed may owe its 3rd(+)
    float wv19 = __shfl(av, 19);
    int wg19 = __shfl(ag, 19);
    unsigned used = (1u << j1) | (1u << j2) | (1u << j3);
    float pv = b3;
    int pg = gbase + (j3 << 6);
    while (__any(BEFORE(pv, pg, wv19, wg19))) {
        unsigned long long act = __ballot(BEFORE(pv, pg, wv19, wg19));
        int L = __ffsll(act) - 1;
        float cv = __shfl(pv, L);
        int cg2 = __shfl(pg, L);
        unsigned long long cfb = __ballot(lane < 20 && BEFORE(cv, cg2, av, ag));
        int p = 20 - __popcll(cfb);
        float upv = __shfl_up(av, 1);
        int upg = __shfl_up(ag, 1);
        if (lane < 20) {
            if (lane > p) { av = upv; ag = upg; }
            else if (lane == p) { av = cv; ag = cg2; }
        }
        if (lane == L) {
            float nb = -INFINITY;
            int nj = 0;
#pragma unroll
            for (int j = 0; j < 16; ++j) {
                float vvv = ((used >> j) & 1u) ? -INFINITY : v[j];
                if (vvv > nb) { nb = vvv; nj = j; }
            }
            used |= 1u << nj;
            pv = nb;
            pg = gbase + (nj << 6);
        }
        wv19 = __shfl(av, 19);
        wg19 = __shfl(ag, 19);
    }

    // ---- merge the two half-top-20s (distances dead; reuse LDS start) ----
    // values at [row*80 + h*20 + lane], indices (ints) at int-offset 640 + same
    __syncthreads();
    if (lane < KNNK) {
        lds[row * 80 + h * 20 + lane] = av;
        ((int*)lds)[640 + row * 80 + h * 20 + lane] = ag;
    }
    __syncthreads();
    if (wave < 4) {
        int r = wave;
        float mv = (lane < 40) ? lds[r * 80 + lane] : -INFINITY;
        int mg = (lane < 40) ? ((int*)lds)[640 + r * 80 + lane] : 0x7fffffff;
#pragma unroll
        for (int size = 2; size <= 64; size <<= 1) {
#pragma unroll
            for (int stride = size >> 1; stride >= 1; stride >>= 1) {
                float ov = __shfl_xor(mv, stride);
                int og = __shfl_xor(mg, stride);
                bool low = (lane & stride) == 0;
                bool asc = (lane & size) == 0;
                bool fwd = BEFORE(mv, mg, ov, og);
                bool take = (low == asc) ? fwd : !fwd;
                mv = take ? mv : ov;
                mg = take ? mg : og;
            }
        }
        if (lane < KNNK) idx_out[((long)b * 2048 + n0 + r) * KNNK + lane] = mg;
    }
}

// ---------------- P = Wa @ f, Q = (Wb - Wa) @ f, stored (B, N, 64) n-major ----------------
__global__ __launch_bounds__(256) void pq_kernel(const float* __restrict__ f, long bstride, int C,
                                                 const float* __restrict__ W, float* __restrict__ P,
                                                 float* __restrict__ Q) {
    __shared__ __align__(16) float wa[64 * 64];
    __shared__ __align__(16) float wq[64 * 64];
    __shared__ __align__(16) float X[64 * 64];
    int b = blockIdx.y, n0 = blockIdx.x * 64, t = threadIdx.x;
    const float* fb = f + (long)b * bstride;
    for (int e = t; e < C * 64; e += 256) {
        int k = e >> 6, c = e & 63;
        float a = W[c * 2 * C + k];
        float bv = W[c * 2 * C + C + k];
        wa[k * 64 + c] = a;
        wq[k * 64 + c] = bv - a;
    }
    for (int e = t; e < C * 64; e += 256) {
        int k = e >> 6, j = e & 63;
        X[e] = fb[k * 2048 + n0 + j];
    }
    __syncthreads();
    int cg = t >> 4, ng = t & 15;
    float accP[4][4] = {}, accQ[4][4] = {};
    for (int k = 0; k < C; ++k) {
        float4 a4 = *(const float4*)(wa + k * 64 + cg * 4);
        float4 q4 = *(const float4*)(wq + k * 64 + cg * 4);
        float4 x4 = *(const float4*)(X + k * 64 + ng * 4);
        float av[4] = {a4.x, a4.y, a4.z, a4.w};
        float qv[4] = {q4.x, q4.y, q4.z, q4.w};
        float xv[4] = {x4.x, x4.y, x4.z, x4.w};
#pragma unroll
        for (int i = 0; i < 4; ++i)
#pragma unroll
            for (int j = 0; j < 4; ++j) {
                accP[i][j] = fmaf(av[i], xv[j], accP[i][j]);
                accQ[i][j] = fmaf(qv[i], xv[j], accQ[i][j]);
            }
    }
#pragma unroll
    for (int j = 0; j < 4; ++j) {
        long n = n0 + ng * 4 + j;
        float4 pv = {accP[0][j], accP[1][j], accP[2][j], accP[3][j]};
        float4 qv = {accQ[0][j], accQ[1][j], accQ[2][j], accQ[3][j]};
        *(float4*)(P + ((long)b * 2048 + n) * 64 + cg * 4) = pv;
        *(float4*)(Q + ((long)b * 2048 + n) * 64 + cg * 4) = qv;
    }
}

// ---------------- EdgeConv layer-2 + max over k, fused (stages 1 & 2) ----------------
__global__ __launch_bounds__(256) void edge2_kernel(
    const float* __restrict__ P, const float* __restrict__ Q, const int* __restrict__ idx,
    const float* __restrict__ W2, const float* __restrict__ sa, const float* __restrict__ ta,
    const float* __restrict__ sb, const float* __restrict__ tb, float* __restrict__ out, int cofs) {
    __shared__ __align__(16) float h1[64 * 164];   // [cin][col], padded
    __shared__ __align__(16) float w2l[64 * 64];   // [cin][cout]
    __shared__ int idxl[160];
    int b = blockIdx.y, n0 = blockIdx.x * 8, t = threadIdx.x;
    if (t < 160) idxl[t] = idx[((long)b * 2048 + n0) * KNNK + t];
    for (int e = t; e < 4096; e += 256) { int co = e >> 6, ci = e & 63; w2l[ci * 64 + co] = W2[e]; }
    __syncthreads();
    for (int it = t; it < 2560; it += 256) {   // 160 cols x 16 channel-quads
        int col = it % 160, cg = it / 160;
        int p = col / 20;
        int j = idxl[col];
        int n = n0 + p;
        float4 pv = *(const float4*)(P + ((long)b * 2048 + j) * 64 + cg * 4);
        float4 qv = *(const float4*)(Q + ((long)b * 2048 + n) * 64 + cg * 4);
        float4 sv = *(const float4*)(sa + cg * 4);
        float4 tv = *(const float4*)(ta + cg * 4);
        h1[(cg * 4 + 0) * 164 + col] = lrelu(fmaf(sv.x, pv.x + qv.x, tv.x));
        h1[(cg * 4 + 1) * 164 + col] = lrelu(fmaf(sv.y, pv.y + qv.y, tv.y));
        h1[(cg * 4 + 2) * 164 + col] = lrelu(fmaf(sv.z, pv.z + qv.z, tv.z));
        h1[(cg * 4 + 3) * 164 + col] = lrelu(fmaf(sv.w, pv.w + qv.w, tv.w));
    }
    __syncthreads();
    int p = t & 7, co2 = t >> 3, c0 = co2 * 2;
    float acc0[20], acc1[20];
#pragma unroll
    for (int q = 0; q < 20; ++q) { acc0[q] = 0.f; acc1[q] = 0.f; }
#pragma unroll 4
    for (int k = 0; k < 64; ++k) {
        float2 w = *(const float2*)(w2l + k * 64 + c0);
        const float* hr = h1 + k * 164 + p * 20;
#pragma unroll
        for (int q = 0; q < 5; ++q) {
            float4 h4 = *(const float4*)(hr + q * 4);
            acc0[q * 4 + 0] = fmaf(w.x, h4.x, acc0[q * 4 + 0]);
            acc0[q * 4 + 1] = fmaf(w.x, h4.y, acc0[q * 4 + 1]);
            acc0[q * 4 + 2] = fmaf(w.x, h4.z, acc0[q * 4 + 2]);
            acc0[q * 4 + 3] = fmaf(w.x, h4.w, acc0[q * 4 + 3]);
            acc1[q * 4 + 0] = fmaf(w.y, h4.x, acc1[q * 4 + 0]);
            acc1[q * 4 + 1] = fmaf(w.y, h4.y, acc1[q * 4 + 1]);
            acc1[q * 4 + 2] = fmaf(w.y, h4.z, acc1[q * 4 + 2]);
            acc1[q * 4 + 3] = fmaf(w.y, h4.w, acc1[q * 4 + 3]);
        }
    }
    float s0 = sb[c0], t0v = tb[c0], s1 = sb[c0 + 1], t1v = tb[c0 + 1];
    float m0 = -INFINITY, m1 = -INFINITY;
#pragma unroll
    for (int q = 0; q < 20; ++q) {
        m0 = fmaxf(m0, lrelu(fmaf(s0, acc0[q], t0v)));
        m1 = fmaxf(m1, lrelu(fmaf(s1, acc1[q], t1v)));
    }
    out[(long)b * (192 * 2048) + (long)(cofs + c0) * 2048 + n0 + p] = m0;
    out[(long)b * (192 * 2048) + (long)(cofs + c0 + 1) * 2048 + n0 + p] = m1;
}

// ---------------- Stage 3: gather + affine + lrelu + max over k ----------------
__global__ __launch_bounds__(256) void edge1_kernel(const float* __restrict__ P, const float* __restrict__ Q,
                                                    const int* __restrict__ idx, const float* __restrict__ s,
                                                    const float* __restrict__ tt, float* __restrict__ out,
                                                    int cofs) {
    __shared__ int idxl[80];
    int b = blockIdx.y, n0 = blockIdx.x * 4, t = threadIdx.x;
    int c = t & 63, p = t >> 6;
    if (t < 80) idxl[t] = idx[((long)b * 2048 + n0) * KNNK + t];
    __syncthreads();
    float qv = Q[((long)b * 2048 + n0 + p) * 64 + c];
    float sc = s[c], tc = tt[c];
    float m = -INFINITY;
    for (int kk = 0; kk < KNNK; ++kk) {
        int j = idxl[p * KNNK + kk];
        float v = P[((long)b * 2048 + j) * 64 + c];
        m = fmaxf(m, lrelu(fmaf(sc, v + qv, tc)));
    }
    out[(long)b * (192 * 2048) + (long)(cofs + c) * 2048 + n0 + p] = m;
}

// ---------------- Generic head GEMM: 128x128 tile, 8x8 per thread ----------------
__global__ __launch_bounds__(256, 4) void gemm_kernel(
    const float* __restrict__ W, int ldw, int Kdim, const float* __restrict__ X, long xbstride,
    const float* __restrict__ s, const float* __restrict__ tvec, const float* __restrict__ bias, int M,
    float* __restrict__ out, long obstride, float* __restrict__ maxout) {
    __shared__ __align__(16) float wl[32 * 132];
    __shared__ __align__(16) float xl[32 * 132];
    int b = blockIdx.z, ct = blockIdx.x * 128, nt = blockIdx.y * 128, t = threadIdx.x;
    const float* Xb = X + (long)b * xbstride;
    int cg = t >> 4, ng = t & 15;
    float acc[8][8];
#pragma unroll
    for (int i = 0; i < 8; ++i)
#pragma unroll
        for (int j = 0; j < 8; ++j) acc[i][j] = 0.f;
    for (int k0 = 0; k0 < Kdim; k0 += 32) {
        __syncthreads();
        for (int e = t; e < 4096; e += 256) {
            int k = e & 31, c = e >> 5;
            wl[k * 132 + c] = W[(long)(ct + c) * ldw + k0 + k];
        }
        for (int e = t; e < 4096; e += 256) {
            int k = e >> 7, j = e & 127;
            xl[k * 132 + j] = Xb[(long)(k0 + k) * 2048 + nt + j];
        }
        __syncthreads();
#pragma unroll 4
        for (int k = 0; k < 32; ++k) {
            float4 wa4 = *(const float4*)(wl + k * 132 + cg * 8);
            float4 wb4 = *(const float4*)(wl + k * 132 + cg * 8 + 4);
            float4 xa4 = *(const float4*)(xl + k * 132 + ng * 4);
            float4 xb4 = *(const float4*)(xl + k * 132 + 64 + ng * 4);
            float wv[8] = {wa4.x, wa4.y, wa4.z, wa4.w, wb4.x, wb4.y, wb4.z, wb4.w};
            float xv[8] = {xa4.x, xa4.y, xa4.z, xa4.w, xb4.x, xb4.y, xb4.z, xb4.w};
#pragma unroll
            for (int i = 0; i < 8; ++i)
#pragma unroll
                for (int j = 0; j < 8; ++j) acc[i][j] = fmaf(wv[i], xv[j], acc[i][j]);
        }
    }
    if (maxout) {
        __syncthreads();
        float* scr = xl;   // 128 x 16 reuse
#pragma unroll
        for (int i = 0; i < 8; ++i) {
            int c = ct + cg * 8 + i;
            float sv = s[c], tv = tvec[c];
            float m = -INFINITY;
#pragma unroll
            for (int j = 0; j < 8; ++j) m = fmaxf(m, lrelu(fmaf(sv, acc[i][j], tv)));
            scr[(cg * 8 + i) * 16 + ng] = m;
        }
        __syncthreads();
        if (t < 128) {
            float m = scr[t * 16];
            for (int j = 1; j < 16; ++j) m = fmaxf(m, scr[t * 16 + j]);
            maxout[((long)b * M + ct + t) * 16 + blockIdx.y] = m;
        }
    } else {
#pragma unroll
        for (int i = 0; i < 8; ++i) {
            int c = ct + cg * 8 + i;
            float bv = bias ? bias[b * M + c] : 0.f;
            float sv = s[c], tv = tvec[c];
            float4 o0, o1;
            o0.x = lrelu(fmaf(sv, acc[i][0] + bv, tv));
            o0.y = lrelu(fmaf(sv, acc[i][1] + bv, tv));
            o0.z = lrelu(fmaf(sv, acc[i][2] + bv, tv));
            o0.w = lrelu(fmaf(sv, acc[i][3] + bv, tv));
            o1.x = lrelu(fmaf(sv, acc[i][4] + bv, tv));
            o1.y = lrelu(fmaf(sv, acc[i][5] + bv, tv));
            o1.z = lrelu(fmaf(sv, acc[i][6] + bv, tv));
            o1.w = lrelu(fmaf(sv, acc[i][7] + bv, tv));
            float* op = out + (long)b * obstride + (long)c * 2048 + nt + ng * 4;
            *(float4*)op = o0;
            *(float4*)(op + 64) = o1;
        }
    }
}

// ---------------- finalize g = max over the 16 n-tile partials ----------------
__global__ __launch_bounds__(256) void gmax_final(const float* __restrict__ ep, float* __restrict__ g) {
    int i = blockIdx.x * 256 + threadIdx.x;   // < 16*1024
    float m = ep[i * 16];
    for (int j = 1; j < 16; ++j) m = fmaxf(m, ep[i * 16 + j]);
    g[i] = m;
}

// ---------------- bias7[b][co] = w7[co, :1024] @ g[b] ----------------
__global__ __launch_bounds__(64) void bias7_kernel(const float* __restrict__ w7, const float* __restrict__ g,
                                                   float* __restrict__ bias7) {
    int o = blockIdx.x;            // b*512 + co
    int b = o >> 9, co = o & 511;
    int lane = threadIdx.x;
    float acc = 0.f;
    for (int j = lane; j < 1024; j += 64) acc = fmaf(w7[(long)co * 1216 + j], g[b * 1024 + j], acc);
#pragma unroll
    for (int off = 32; off >= 1; off >>= 1) acc += __shfl_xor(acc, off);
    if (lane == 0) bias7[o] = acc;
}

// ---------------- y[b][n] = sigmoid(w9 @ h8[:, n]) ----------------
__global__ __launch_bounds__(256) void w9_kernel(const float* __restrict__ w9, const float* __restrict__ h8,
                                                 float* __restrict__ out) {
    int i = blockIdx.x * 256 + threadIdx.x;   // over B*N
    int b = i >> 11, n = i & 2047;
    const float* hb = h8 + (long)b * 256 * 2048 + n;
    float acc = 0.f;
    for (int c = 0; c < 256; ++c) acc = fmaf(w9[c], hb[c * 2048], acc);
    out[i] = 1.f / (1.f + expf(-acc));
}

extern "C" void kernel_launch(void* const* d_in, const int* in_sizes, int n_in,
                              void* d_out, int out_size, void* d_ws, size_t ws_size,
                              hipStream_t stream) {
    (void)in_sizes; (void)n_in; (void)out_size; (void)ws_size;
    const float* x  = (const float*)d_in[0];
    const float* w1 = (const float*)d_in[1];
    const float* w2 = (const float*)d_in[2];
    const float* w3 = (const float*)d_in[3];
    const float* w4 = (const float*)d_in[4];
    const float* w5 = (const float*)d_in[5];
    const float* w6 = (const float*)d_in[6];
    const float* w7 = (const float*)d_in[7];
    const float* w8 = (const float*)d_in[8];
    const float* w9 = (const float*)d_in[9];
    const float* s1 = (const float*)d_in[10]; const float* t1 = (const float*)d_in[11];
    const float* s2 = (const float*)d_in[12]; const float* t2 = (const float*)d_in[13];
    const float* s3 = (const float*)d_in[14]; const float* t3 = (const float*)d_in[15];
    const float* s4 = (const float*)d_in[16]; const float* t4 = (const float*)d_in[17];
    const float* s5 = (const float*)d_in[18]; const float* t5 = (const float*)d_in[19];
    const float* s6 = (const float*)d_in[20]; const float* t6 = (const float*)d_in[21];
    const float* s7 = (const float*)d_in[22]; const float* t7 = (const float*)d_in[23];
    const float* s8 = (const float*)d_in[24]; const float* t8 = (const float*)d_in[25];

    // workspace partition (floats)
    float* cat = (float*)d_ws;                          // 16*192*2048
    float* xxb = cat + (long)16 * 192 * 2048;           // 16*2048
    int*   idxb = (int*)(xxb + 16 * 2048);              // 16*2048*20 ints
    float* P  = (float*)(idxb + (long)16 * 2048 * 20);  // 16*2048*64
    float* Q  = P + (long)16 * 2048 * 64;               // 16*2048*64
    float* ep = Q + (long)16 * 2048 * 64;               // 16*1024*16
    float* g  = ep + 16 * 1024 * 16;                    // 16*1024
    float* b7 = g + 16 * 1024;                          // 16*512
    float* h7 = b7 + 16 * 512;                          // 16*512*2048
    float* h8 = h7 + (long)16 * 512 * 2048;             // 16*256*2048

    dim3 blk(256);
    dim3 blk512(512);
    long catstride = 192 * 2048;

    // ---- stage 1 (C=2) ----
    xx_kernel<<<128, blk, 0, stream>>>(x, 2 * 2048, 2, xxb);
    knn_kernel<<<dim3(512, 16), blk512, 0, stream>>>(x, 2 * 2048, 2, xxb, idxb);
    pq_kernel<<<dim3(32, 16), blk, 0, stream>>>(x, 2 * 2048, 2, w1, P, Q);
    edge2_kernel<<<dim3(256, 16), blk, 0, stream>>>(P, Q, idxb, w2, s1, t1, s2, t2, cat, 0);
    // ---- stage 2 (C=64 on x1) ----
    xx_kernel<<<128, blk, 0, stream>>>(cat, catstride, 64, xxb);
    knn_kernel<<<dim3(512, 16), blk512, 0, stream>>>(cat, catstride, 64, xxb, idxb);
    pq_kernel<<<dim3(32, 16), blk, 0, stream>>>(cat, catstride, 64, w3, P, Q);
    edge2_kernel<<<dim3(256, 16), blk, 0, stream>>>(P, Q, idxb, w4, s3, t3, s4, t4, cat, 64);
    // ---- stage 3 (C=64 on x2) ----
    xx_kernel<<<128, blk, 0, stream>>>(cat + 64 * 2048, catstride, 64, xxb);
    knn_kernel<<<dim3(512, 16), blk512, 0, stream>>>(cat + 64 * 2048, catstride, 64, xxb, idxb);
    pq_kernel<<<dim3(32, 16), blk, 0, stream>>>(cat + 64 * 2048, catstride, 64, w5, P, Q);
    edge1_kernel<<<dim3(512, 16), blk, 0, stream>>>(P, Q, idxb, s5, t5, cat, 128);
    // ---- head ----
    gemm_kernel<<<dim3(8, 16, 16), blk, 0, stream>>>(w6, 192, 192, cat, catstride, s6, t6, nullptr, 1024,
                                                     nullptr, 0, ep);
    gmax_final<<<64, blk, 0, stream>>>(ep, g);
    bias7_kernel<<<dim3(16 * 512), dim3(64), 0, stream>>>(w7, g, b7);
    gemm_kernel<<<dim3(4, 16, 16), blk, 0, stream>>>(w7 + 1024, 1216, 192, cat, catstride, s7, t7, b7, 512,
                                                     h7, (long)512 * 2048, nullptr);
    gemm_kernel<<<dim3(2, 16, 16), blk, 0, stream>>>(w8, 512, 512, h7, (long)512 * 2048, s8, t8, nullptr, 256,
                                                     h8, (long)256 * 2048, nullptr);
    w9_kernel<<<128, blk, 0, stream>>>(w9, h8, (float*)d_out);
}

// Round 7
// 1354.115 us; speedup vs baseline: 1.1165x; 1.0704x over previous
//
#include <hip/hip_runtime.h>
#include <math.h>

#define KNNK 20
#define BEFORE(v1, g1, v2, g2) (((v1) > (v2)) || ((v1) == (v2) && (g1) < (g2)))

__device__ __forceinline__ float lrelu(float v) { return v >= 0.f ? v : 0.2f * v; }

// ---------------- xx[b][n] = sum_c f[b][c][n]^2 ----------------
__global__ __launch_bounds__(256) void xx_kernel(const float* __restrict__ f, long bstride, int C,
                                                 float* __restrict__ xx) {
    int i = blockIdx.x * 256 + threadIdx.x;   // over B*N
    int b = i >> 11, n = i & 2047;
    const float* fb = f + (long)b * bstride;
    float s = 0.f;
    for (int c = 0; c < C; ++c) { float v = fb[c * 2048 + n]; s = fmaf(v, v, s); }
    xx[i] = s;
}

// ---------------- KNN: 4-row strip, 256 threads (4 waves), ONE wave per row ----------------
// LDS 32 KB -> 5 blocks/CU = 20 waves/CU. Thread owns 4 rows x 8 cols in Gram (32 fma/c).
// Selection: wave w owns row w: v[32] register-resident, per-lane top-3, single
// 128-candidate bitonic sort by (value desc, index asc) + repair loop. No merge step.
__global__ __launch_bounds__(256, 4) void knn_kernel(const float* __restrict__ f, long bstride, int C,
                                                     const float* __restrict__ xx, int* __restrict__ idx_out) {
    __shared__ __align__(16) float lds[4 * 2048];
    int b = blockIdx.y;
    int n0 = blockIdx.x * 4;
    int t = threadIdx.x;
    const float* fb = f + (long)b * bstride;

    // stage center block A[c][j] = f[c][n0+j]
    for (int e = t; e < C * 4; e += 256) {
        int c = e >> 2, j = e & 3;
        lds[e] = fb[c * 2048 + n0 + j];
    }
    __syncthreads();

    // Gram: all 4 rows, cols m0..m0+7
    int m0 = t * 8;
    float acc[4][8];
#pragma unroll
    for (int i = 0; i < 4; ++i)
#pragma unroll
        for (int j = 0; j < 8; ++j) acc[i][j] = 0.f;
    for (int c = 0; c < C; ++c) {
        float4 b0 = *(const float4*)(fb + c * 2048 + m0);
        float4 b1 = *(const float4*)(fb + c * 2048 + m0 + 4);
        float bv8[8] = {b0.x, b0.y, b0.z, b0.w, b1.x, b1.y, b1.z, b1.w};
        float4 a4 = *(const float4*)(lds + c * 4);
        float av4[4] = {a4.x, a4.y, a4.z, a4.w};
#pragma unroll
        for (int i = 0; i < 4; ++i)
#pragma unroll
            for (int j = 0; j < 8; ++j) acc[i][j] = fmaf(av4[i], bv8[j], acc[i][j]);
    }
    float xn[4];
#pragma unroll
    for (int i = 0; i < 4; ++i) xn[i] = xx[b * 2048 + n0 + i];
    float4 x0 = *(const float4*)(xx + b * 2048 + m0);
    float4 x1 = *(const float4*)(xx + b * 2048 + m0 + 4);
    float xm[8] = {x0.x, x0.y, x0.z, x0.w, x1.x, x1.y, x1.z, x1.w};

    __syncthreads();   // A region fully consumed before distances overwrite it
#pragma unroll
    for (int i = 0; i < 4; ++i) {
        float4 o0, o1;
        o0.x = (2.f * acc[i][0] - xn[i]) - xm[0];
        o0.y = (2.f * acc[i][1] - xn[i]) - xm[1];
        o0.z = (2.f * acc[i][2] - xn[i]) - xm[2];
        o0.w = (2.f * acc[i][3] - xn[i]) - xm[3];
        o1.x = (2.f * acc[i][4] - xn[i]) - xm[4];
        o1.y = (2.f * acc[i][5] - xn[i]) - xm[5];
        o1.z = (2.f * acc[i][6] - xn[i]) - xm[6];
        o1.w = (2.f * acc[i][7] - xn[i]) - xm[7];
        *(float4*)(lds + i * 2048 + m0) = o0;
        *(float4*)(lds + i * 2048 + m0 + 4) = o1;
    }
    __syncthreads();

    // ---- selection: wave w owns row w, register-resident ----
    int wave = t >> 6, lane = t & 63;
    const float* srow = lds + wave * 2048;
    float v[32];
#pragma unroll
    for (int j = 0; j < 32; ++j) v[j] = srow[lane + 64 * j];   // global col = lane + 64*j

    // per-lane top-3 (strict '>' keeps earliest index among equals)
    float b1 = -INFINITY, b2 = -INFINITY, b3 = -INFINITY;
    int j1 = 0, j2 = 0, j3 = 0;
#pragma unroll
    for (int j = 0; j < 32; ++j) {
        float vv = v[j];
        bool c1 = vv > b1;
        bool c2 = vv > b2;
        bool c3 = vv > b3;
        b3 = c2 ? b2 : (c3 ? vv : b3);
        j3 = c2 ? j2 : (c3 ? j : j3);
        b2 = c1 ? b1 : (c2 ? vv : b2);
        j2 = c1 ? j1 : (c2 ? j : j2);
        b1 = c1 ? vv : b1;
        j1 = c1 ? j : j1;
    }

    // bitonic sort of 128 candidates (2 per lane)
    float av = b1, bv = b2;
    int ag = lane + (j1 << 6), bg = lane + (j2 << 6);
#pragma unroll
    for (int size = 2; size <= 128; size <<= 1) {
#pragma unroll
        for (int stride = size >> 1; stride >= 1; stride >>= 1) {
            if (stride == 64) {
                bool keep = BEFORE(av, ag, bv, bg);
                float tv = keep ? av : bv;
                int tg = keep ? ag : bg;
                bv = keep ? bv : av; bg = keep ? bg : ag;
                av = tv; ag = tg;
            } else {
                float oav = __shfl_xor(av, stride), obv = __shfl_xor(bv, stride);
                int oag = __shfl_xor(ag, stride), obg = __shfl_xor(bg, stride);
                bool low = (lane & stride) == 0;
                bool ascA = (lane & size) == 0;
                bool ascB = (((64 + lane) & size) == 0);
                bool fA = BEFORE(av, ag, oav, oag);
                bool fB = BEFORE(bv, bg, obv, obg);
                bool tA = (low == ascA) ? fA : !fA;
                bool tB = (low == ascB) ? fB : !fB;
                av = tA ? av : oav; ag = tA ? ag : oag;
                bv = tB ? bv : obv; bg = tB ? bg : obg;
            }
        }
    }
    // lanes 0..19 hold ranks 0..19

    // repair: lane whose top-2 both placed may owe its 3rd(+)
    float wv19 = __shfl(av, 19);
    int wg19 = __shfl(ag, 19);
    unsigned used = (1u << j1) | (1u << j2) | (1u << j3);
    float pv = b3;
    int pg = lane + (j3 << 6);
    while (__any(BEFORE(pv, pg, wv19, wg19))) {
        unsigned long long act = __ballot(BEFORE(pv, pg, wv19, wg19));
        int L = __ffsll(act) - 1;
        float cv = __shfl(pv, L);
        int cg2 = __shfl(pg, L);
        unsigned long long cfb = __ballot(lane < 20 && BEFORE(cv, cg2, av, ag));
        int p = 20 - __popcll(cfb);
        float upv = __shfl_up(av, 1);
        int upg = __shfl_up(ag, 1);
        if (lane < 20) {
            if (lane > p) { av = upv; ag = upg; }
            else if (lane == p) { av = cv; ag = cg2; }
        }
        if (lane == L) {
            float nb = -INFINITY;
            int nj = 0;
#pragma unroll
            for (int j = 0; j < 32; ++j) {
                float vvv = ((used >> j) & 1u) ? -INFINITY : v[j];
                if (vvv > nb) { nb = vvv; nj = j; }
            }
            used |= 1u << nj;
            pv = nb;
            pg = lane + (nj << 6);
        }
        wv19 = __shfl(av, 19);
        wg19 = __shfl(ag, 19);
    }
    if (lane < KNNK) idx_out[((long)b * 2048 + n0 + wave) * KNNK + lane] = ag;
}

// ---------------- P = Wa @ f, Q = (Wb - Wa) @ f, stored (B, N, 64) n-major ----------------
__global__ __launch_bounds__(256) void pq_kernel(const float* __restrict__ f, long bstride, int C,
                                                 const float* __restrict__ W, float* __restrict__ P,
                                                 float* __restrict__ Q) {
    __shared__ __align__(16) float wa[64 * 64];
    __shared__ __align__(16) float wq[64 * 64];
    __shared__ __align__(16) float X[64 * 64];
    int b = blockIdx.y, n0 = blockIdx.x * 64, t = threadIdx.x;
    const float* fb = f + (long)b * bstride;
    for (int e = t; e < C * 64; e += 256) {
        int k = e >> 6, c = e & 63;
        float a = W[c * 2 * C + k];
        float bv = W[c * 2 * C + C + k];
        wa[k * 64 + c] = a;
        wq[k * 64 + c] = bv - a;
    }
    for (int e = t; e < C * 64; e += 256) {
        int k = e >> 6, j = e & 63;
        X[e] = fb[k * 2048 + n0 + j];
    }
    __syncthreads();
    int cg = t >> 4, ng = t & 15;
    float accP[4][4] = {}, accQ[4][4] = {};
    for (int k = 0; k < C; ++k) {
        float4 a4 = *(const float4*)(wa + k * 64 + cg * 4);
        float4 q4 = *(const float4*)(wq + k * 64 + cg * 4);
        float4 x4 = *(const float4*)(X + k * 64 + ng * 4);
        float av[4] = {a4.x, a4.y, a4.z, a4.w};
        float qv[4] = {q4.x, q4.y, q4.z, q4.w};
        float xv[4] = {x4.x, x4.y, x4.z, x4.w};
#pragma unroll
        for (int i = 0; i < 4; ++i)
#pragma unroll
            for (int j = 0; j < 4; ++j) {
                accP[i][j] = fmaf(av[i], xv[j], accP[i][j]);
                accQ[i][j] = fmaf(qv[i], xv[j], accQ[i][j]);
            }
    }
#pragma unroll
    for (int j = 0; j < 4; ++j) {
        long n = n0 + ng * 4 + j;
        float4 pv = {accP[0][j], accP[1][j], accP[2][j], accP[3][j]};
        float4 qv = {accQ[0][j], accQ[1][j], accQ[2][j], accQ[3][j]};
        *(float4*)(P + ((long)b * 2048 + n) * 64 + cg * 4) = pv;
        *(float4*)(Q + ((long)b * 2048 + n) * 64 + cg * 4) = qv;
    }
}

// ---------------- EdgeConv layer-2 + max over k, fused (stages 1 & 2) ----------------
__global__ __launch_bounds__(256) void edge2_kernel(
    const float* __restrict__ P, const float* __restrict__ Q, const int* __restrict__ idx,
    const float* __restrict__ W2, const float* __restrict__ sa, const float* __restrict__ ta,
    const float* __restrict__ sb, const float* __restrict__ tb, float* __restrict__ out, int cofs) {
    __shared__ __align__(16) float h1[64 * 164];   // [cin][col], padded
    __shared__ __align__(16) float w2l[64 * 64];   // [cin][cout]
    __shared__ int idxl[160];
    int b = blockIdx.y, n0 = blockIdx.x * 8, t = threadIdx.x;
    if (t < 160) idxl[t] = idx[((long)b * 2048 + n0) * KNNK + t];
    for (int e = t; e < 4096; e += 256) { int co = e >> 6, ci = e & 63; w2l[ci * 64 + co] = W2[e]; }
    __syncthreads();
    for (int it = t; it < 2560; it += 256) {   // 160 cols x 16 channel-quads
        int col = it % 160, cg = it / 160;
        int p = col / 20;
        int j = idxl[col];
        int n = n0 + p;
        float4 pv = *(const float4*)(P + ((long)b * 2048 + j) * 64 + cg * 4);
        float4 qv = *(const float4*)(Q + ((long)b * 2048 + n) * 64 + cg * 4);
        float4 sv = *(const float4*)(sa + cg * 4);
        float4 tv = *(const float4*)(ta + cg * 4);
        h1[(cg * 4 + 0) * 164 + col] = lrelu(fmaf(sv.x, pv.x + qv.x, tv.x));
        h1[(cg * 4 + 1) * 164 + col] = lrelu(fmaf(sv.y, pv.y + qv.y, tv.y));
        h1[(cg * 4 + 2) * 164 + col] = lrelu(fmaf(sv.z, pv.z + qv.z, tv.z));
        h1[(cg * 4 + 3) * 164 + col] = lrelu(fmaf(sv.w, pv.w + qv.w, tv.w));
    }
    __syncthreads();
    int p = t & 7, co2 = t >> 3, c0 = co2 * 2;
    float acc0[20], acc1[20];
#pragma unroll
    for (int q = 0; q < 20; ++q) { acc0[q] = 0.f; acc1[q] = 0.f; }
#pragma unroll 4
    for (int k = 0; k < 64; ++k) {
        float2 w = *(const float2*)(w2l + k * 64 + c0);
        const float* hr = h1 + k * 164 + p * 20;
#pragma unroll
        for (int q = 0; q < 5; ++q) {
            float4 h4 = *(const float4*)(hr + q * 4);
            acc0[q * 4 + 0] = fmaf(w.x, h4.x, acc0[q * 4 + 0]);
            acc0[q * 4 + 1] = fmaf(w.x, h4.y, acc0[q * 4 + 1]);
            acc0[q * 4 + 2] = fmaf(w.x, h4.z, acc0[q * 4 + 2]);
            acc0[q * 4 + 3] = fmaf(w.x, h4.w, acc0[q * 4 + 3]);
            acc1[q * 4 + 0] = fmaf(w.y, h4.x, acc1[q * 4 + 0]);
            acc1[q * 4 + 1] = fmaf(w.y, h4.y, acc1[q * 4 + 1]);
            acc1[q * 4 + 2] = fmaf(w.y, h4.z, acc1[q * 4 + 2]);
            acc1[q * 4 + 3] = fmaf(w.y, h4.w, acc1[q * 4 + 3]);
        }
    }
    float s0 = sb[c0], t0v = tb[c0], s1 = sb[c0 + 1], t1v = tb[c0 + 1];
    float m0 = -INFINITY, m1 = -INFINITY;
#pragma unroll
    for (int q = 0; q < 20; ++q) {
        m0 = fmaxf(m0, lrelu(fmaf(s0, acc0[q], t0v)));
        m1 = fmaxf(m1, lrelu(fmaf(s1, acc1[q], t1v)));
    }
    out[(long)b * (192 * 2048) + (long)(cofs + c0) * 2048 + n0 + p] = m0;
    out[(long)b * (192 * 2048) + (long)(cofs + c0 + 1) * 2048 + n0 + p] = m1;
}

// ---------------- Stage 3: gather + affine + lrelu + max over k ----------------
__global__ __launch_bounds__(256) void edge1_kernel(const float* __restrict__ P, const float* __restrict__ Q,
                                                    const int* __restrict__ idx, const float* __restrict__ s,
                                                    const float* __restrict__ tt, float* __restrict__ out,
                                                    int cofs) {
    __shared__ int idxl[80];
    int b = blockIdx.y, n0 = blockIdx.x * 4, t = threadIdx.x;
    int c = t & 63, p = t >> 6;
    if (t < 80) idxl[t] = idx[((long)b * 2048 + n0) * KNNK + t];
    __syncthreads();
    float qv = Q[((long)b * 2048 + n0 + p) * 64 + c];
    float sc = s[c], tc = tt[c];
    float m = -INFINITY;
    for (int kk = 0; kk < KNNK; ++kk) {
        int j = idxl[p * KNNK + kk];
        float v = P[((long)b * 2048 + j) * 64 + c];
        m = fmaxf(m, lrelu(fmaf(sc, v + qv, tc)));
    }
    out[(long)b * (192 * 2048) + (long)(cofs + c) * 2048 + n0 + p] = m;
}

// ---------------- Generic head GEMM: 128x128 tile, 8x8 per thread ----------------
__global__ __launch_bounds__(256, 4) void gemm_kernel(
    const float* __restrict__ W, int ldw, int Kdim, const float* __restrict__ X, long xbstride,
    const float* __restrict__ s, const float* __restrict__ tvec, const float* __restrict__ bias, int M,
    float* __restrict__ out, long obstride, float* __restrict__ maxout) {
    __shared__ __align__(16) float wl[32 * 132];
    __shared__ __align__(16) float xl[32 * 132];
    int b = blockIdx.z, ct = blockIdx.x * 128, nt = blockIdx.y * 128, t = threadIdx.x;
    const float* Xb = X + (long)b * xbstride;
    int cg = t >> 4, ng = t & 15;
    float acc[8][8];
#pragma unroll
    for (int i = 0; i < 8; ++i)
#pragma unroll
        for (int j = 0; j < 8; ++j) acc[i][j] = 0.f;
    for (int k0 = 0; k0 < Kdim; k0 += 32) {
        __syncthreads();
        for (int e = t; e < 4096; e += 256) {
            int k = e & 31, c = e >> 5;
            wl[k * 132 + c] = W[(long)(ct + c) * ldw + k0 + k];
        }
        for (int e = t; e < 4096; e += 256) {
            int k = e >> 7, j = e & 127;
            xl[k * 132 + j] = Xb[(long)(k0 + k) * 2048 + nt + j];
        }
        __syncthreads();
#pragma unroll 4
        for (int k = 0; k < 32; ++k) {
            float4 wa4 = *(const float4*)(wl + k * 132 + cg * 8);
            float4 wb4 = *(const float4*)(wl + k * 132 + cg * 8 + 4);
            float4 xa4 = *(const float4*)(xl + k * 132 + ng * 4);
            float4 xb4 = *(const float4*)(xl + k * 132 + 64 + ng * 4);
            float wv[8] = {wa4.x, wa4.y, wa4.z, wa4.w, wb4.x, wb4.y, wb4.z, wb4.w};
            float xv[8] = {xa4.x, xa4.y, xa4.z, xa4.w, xb4.x, xb4.y, xb4.z, xb4.w};
#pragma unroll
            for (int i = 0; i < 8; ++i)
#pragma unroll
                for (int j = 0; j < 8; ++j) acc[i][j] = fmaf(wv[i], xv[j], acc[i][j]);
        }
    }
    if (maxout) {
        __syncthreads();
        float* scr = xl;   // 128 x 16 reuse
#pragma unroll
        for (int i = 0; i < 8; ++i) {
            int c = ct + cg * 8 + i;
            float sv = s[c], tv = tvec[c];
            float m = -INFINITY;
#pragma unroll
            for (int j = 0; j < 8; ++j) m = fmaxf(m, lrelu(fmaf(sv, acc[i][j], tv)));
            scr[(cg * 8 + i) * 16 + ng] = m;
        }
        __syncthreads();
        if (t < 128) {
            float m = scr[t * 16];
            for (int j = 1; j < 16; ++j) m = fmaxf(m, scr[t * 16 + j]);
            maxout[((long)b * M + ct + t) * 16 + blockIdx.y] = m;
        }
    } else {
#pragma unroll
        for (int i = 0; i < 8; ++i) {
            int c = ct + cg * 8 + i;
            float bv = bias ? bias[b * M + c] : 0.f;
            float sv = s[c], tv = tvec[c];
            float4 o0, o1;
            o0.x = lrelu(fmaf(sv, acc[i][0] + bv, tv));
            o0.y = lrelu(fmaf(sv, acc[i][1] + bv, tv));
            o0.z = lrelu(fmaf(sv, acc[i][2] + bv, tv));
            o0.w = lrelu(fmaf(sv, acc[i][3] + bv, tv));
            o1.x = lrelu(fmaf(sv, acc[i][4] + bv, tv));
            o1.y = lrelu(fmaf(sv, acc[i][5] + bv, tv));
            o1.z = lrelu(fmaf(sv, acc[i][6] + bv, tv));
            o1.w = lrelu(fmaf(sv, acc[i][7] + bv, tv));
            float* op = out + (long)b * obstride + (long)c * 2048 + nt + ng * 4;
            *(float4*)op = o0;
            *(float4*)(op + 64) = o1;
        }
    }
}

// ---------------- finalize g = max over the 16 n-tile partials ----------------
__global__ __launch_bounds__(256) void gmax_final(const float* __restrict__ ep, float* __restrict__ g) {
    int i = blockIdx.x * 256 + threadIdx.x;   // < 16*1024
    float m = ep[i * 16];
    for (int j = 1; j < 16; ++j) m = fmaxf(m, ep[i * 16 + j]);
    g[i] = m;
}

// ---------------- bias7[b][co] = w7[co, :1024] @ g[b] ----------------
__global__ __launch_bounds__(64) void bias7_kernel(const float* __restrict__ w7, const float* __restrict__ g,
                                                   float* __restrict__ bias7) {
    int o = blockIdx.x;            // b*512 + co
    int b = o >> 9, co = o & 511;
    int lane = threadIdx.x;
    float acc = 0.f;
    for (int j = lane; j < 1024; j += 64) acc = fmaf(w7[(long)co * 1216 + j], g[b * 1024 + j], acc);
#pragma unroll
    for (int off = 32; off >= 1; off >>= 1) acc += __shfl_xor(acc, off);
    if (lane == 0) bias7[o] = acc;
}

// ---------------- y[b][n] = sigmoid(w9 @ h8[:, n]) ----------------
__global__ __launch_bounds__(256) void w9_kernel(const float* __restrict__ w9, const float* __restrict__ h8,
                                                 float* __restrict__ out) {
    int i = blockIdx.x * 256 + threadIdx.x;   // over B*N
    int b = i >> 11, n = i & 2047;
    const float* hb = h8 + (long)b * 256 * 2048 + n;
    float acc = 0.f;
    for (int c = 0; c < 256; ++c) acc = fmaf(w9[c], hb[c * 2048], acc);
    out[i] = 1.f / (1.f + expf(-acc));
}

extern "C" void kernel_launch(void* const* d_in, const int* in_sizes, int n_in,
                              void* d_out, int out_size, void* d_ws, size_t ws_size,
                              hipStream_t stream) {
    (void)in_sizes; (void)n_in; (void)out_size; (void)ws_size;
    const float* x  = (const float*)d_in[0];
    const float* w1 = (const float*)d_in[1];
    const float* w2 = (const float*)d_in[2];
    const float* w3 = (const float*)d_in[3];
    const float* w4 = (const float*)d_in[4];
    const float* w5 = (const float*)d_in[5];
    const float* w6 = (const float*)d_in[6];
    const float* w7 = (const float*)d_in[7];
    const float* w8 = (const float*)d_in[8];
    const float* w9 = (const float*)d_in[9];
    const float* s1 = (const float*)d_in[10]; const float* t1 = (const float*)d_in[11];
    const float* s2 = (const float*)d_in[12]; const float* t2 = (const float*)d_in[13];
    const float* s3 = (const float*)d_in[14]; const float* t3 = (const float*)d_in[15];
    const float* s4 = (const float*)d_in[16]; const float* t4 = (const float*)d_in[17];
    const float* s5 = (const float*)d_in[18]; const float* t5 = (const float*)d_in[19];
    const float* s6 = (const float*)d_in[20]; const float* t6 = (const float*)d_in[21];
    const float* s7 = (const float*)d_in[22]; const float* t7 = (const float*)d_in[23];
    const float* s8 = (const float*)d_in[24]; const float* t8 = (const float*)d_in[25];

    // workspace partition (floats)
    float* cat = (float*)d_ws;                          // 16*192*2048
    float* xxb = cat + (long)16 * 192 * 2048;           // 16*2048
    int*   idxb = (int*)(xxb + 16 * 2048);              // 16*2048*20 ints
    float* P  = (float*)(idxb + (long)16 * 2048 * 20);  // 16*2048*64
    float* Q  = P + (long)16 * 2048 * 64;               // 16*2048*64
    float* ep = Q + (long)16 * 2048 * 64;               // 16*1024*16
    float* g  = ep + 16 * 1024 * 16;                    // 16*1024
    float* b7 = g + 16 * 1024;                          // 16*512
    float* h7 = b7 + 16 * 512;                          // 16*512*2048
    float* h8 = h7 + (long)16 * 512 * 2048;             // 16*256*2048

    dim3 blk(256);
    long catstride = 192 * 2048;

    // ---- stage 1 (C=2) ----
    xx_kernel<<<128, blk, 0, stream>>>(x, 2 * 2048, 2, xxb);
    knn_kernel<<<dim3(512, 16), blk, 0, stream>>>(x, 2 * 2048, 2, xxb, idxb);
    pq_kernel<<<dim3(32, 16), blk, 0, stream>>>(x, 2 * 2048, 2, w1, P, Q);
    edge2_kernel<<<dim3(256, 16), blk, 0, stream>>>(P, Q, idxb, w2, s1, t1, s2, t2, cat, 0);
    // ---- stage 2 (C=64 on x1) ----
    xx_kernel<<<128, blk, 0, stream>>>(cat, catstride, 64, xxb);
    knn_kernel<<<dim3(512, 16), blk, 0, stream>>>(cat, catstride, 64, xxb, idxb);
    pq_kernel<<<dim3(32, 16), blk, 0, stream>>>(cat, catstride, 64, w3, P, Q);
    edge2_kernel<<<dim3(256, 16), blk, 0, stream>>>(P, Q, idxb, w4, s3, t3, s4, t4, cat, 64);
    // ---- stage 3 (C=64 on x2) ----
    xx_kernel<<<128, blk, 0, stream>>>(cat + 64 * 2048, catstride, 64, xxb);
    knn_kernel<<<dim3(512, 16), blk, 0, stream>>>(cat + 64 * 2048, catstride, 64, xxb, idxb);
    pq_kernel<<<dim3(32, 16), blk, 0, stream>>>(cat + 64 * 2048, catstride, 64, w5, P, Q);
    edge1_kernel<<<dim3(512, 16), blk, 0, stream>>>(P, Q, idxb, s5, t5, cat, 128);
    // ---- head ----
    gemm_kernel<<<dim3(8, 16, 16), blk, 0, stream>>>(w6, 192, 192, cat, catstride, s6, t6, nullptr, 1024,
                                                     nullptr, 0, ep);
    gmax_final<<<64, blk, 0, stream>>>(ep, g);
    bias7_kernel<<<dim3(16 * 512), dim3(64), 0, stream>>>(w7, g, b7);
    gemm_kernel<<<dim3(4, 16, 16), blk, 0, stream>>>(w7 + 1024, 1216, 192, cat, catstride, s7, t7, b7, 512,
                                                     h7, (long)512 * 2048, nullptr);
    gemm_kernel<<<dim3(2, 16, 16), blk, 0, stream>>>(w8, 512, 512, h7, (long)512 * 2048, s8, t8, nullptr, 256,
                                                     h8, (long)256 * 2048, nullptr);
    w9_kernel<<<128, blk, 0, stream>>>(w9, h8, (float*)d_out);
}